// Round 16
// baseline (123.449 us; speedup 1.0000x reference)
//
#include <hip/hip_runtime.h>

// Laplacian pyramid loss via linearity: pyr(p) - pyr(t) = pyr(p - t).
// R16: the one untested matrix cell. Six structures pin L0 at 40+-3us, but
// load-pipelining (VGPR) and block concurrency were never simultaneously
// high: R4 VGPR12/52%occ=2.0TB/s, R5 VGPR36/44%=2.35, R12 VGPR16/57%=1.2
// (launch_bounds(256,8) crushed regs -> serialized loads). This round: R12's
// TH=16 fused tile VERBATIM (absmax 0) with launch_bounds(256,4) -> VGPR
// budget 128 (staging stays pipelined) AND 4 blocks/CU. If L0 >= 38us again,
// the matrix is complete and the plateau is structural -> revert + declare.

__device__ __forceinline__ int reflect_i(int m, int S) {
    if (m < 0) m = -m;
    if (m >= S) m = 2 * S - 2 - m;
    return m;
}

__device__ __forceinline__ void wg_barrier() {
    asm volatile("s_waitcnt lgkmcnt(0)" ::: "memory");
    __builtin_amdgcn_s_barrier();
}

// cur tile: rows ty0-4 .. ty0+TH+2 (RC=TH+7), cols tx0-8 .. tx0+TW+7 (WC=TW+16)
// down tile + halo: rows yd0-1 .. yd0+TH/2, cols xd0-1 .. xd0+TW/2
template <int TW, int TH, int L0>
__global__ __launch_bounds__(256, 4)
void fused_kernel(const float* __restrict__ a, const float* __restrict__ b,
                  float* __restrict__ dwn, float* __restrict__ acc,
                  int S, float scale) {
    const int D = S >> 1;
    const int nx = S / TW, ny = S / TH;
    constexpr int RC = TH + 7;
    constexpr int WC = TW + 16;
    constexpr int C4 = WC / 4;
    constexpr int CH = TW / 2 + 2;
    constexpr int RD = TH / 2 + 2;
    constexpr int HS = CH + 2;
    constexpr int TOT = RC * C4;
    constexpr int UN = (TOT + 255) / 256;

    __shared__ float Lc[RC][WC];
    __shared__ float Lh[RC][HS];
    __shared__ float Ld[RD][HS];

    int bid = blockIdx.x;
    int bx = bid % nx;
    int by = (bid / nx) % ny;
    int n  = bid / (nx * ny);
    int tx0 = bx * TW, ty0 = by * TH;
    int xd0 = tx0 >> 1, yd0 = ty0 >> 1;
    size_t base = (size_t)n * S * S;
    int tid = threadIdx.x;

    // ---- phase 1a: issue ALL global loads (register arrays, static unroll)
    float4 va[UN], vb[UN];
    bool ok[UN];
    #pragma unroll
    for (int u = 0; u < UN; u++) {
        int i = tid + 256 * u;
        int r = i / C4, q = i % C4;
        int gc = tx0 - 8 + 4 * q;
        ok[u] = (i < TOT) && (gc >= 0) && (gc <= S - 4);
        if (ok[u]) {
            int gy = reflect_i(ty0 - 4 + r, S);
            va[u] = *(const float4*)(a + base + (size_t)gy * S + gc);
            if constexpr (L0) vb[u] = *(const float4*)(b + base + (size_t)gy * S + gc);
        }
    }
    // ---- phase 1b: write to LDS
    #pragma unroll
    for (int u = 0; u < UN; u++) {
        if (ok[u]) {
            int i = tid + 256 * u;
            int r = i / C4, q = i % C4;
            float4 v = va[u];
            if constexpr (L0) {
                v.x -= vb[u].x; v.y -= vb[u].y; v.z -= vb[u].z; v.w -= vb[u].w;
            }
            *(float4*)&Lc[r][4 * q] = v;
        }
    }
    __syncthreads();
    // column reflect patches (block-uniform conditions)
    if (tx0 == 0) {
        for (int i = tid; i < RC * 4; i += 256) {
            int r = i >> 2, j = i & 3;
            Lc[r][4 + j] = Lc[r][12 - j];          // col -4+j <- col 4-j
        }
    }
    if (tx0 + TW == S) {
        for (int i = tid; i < RC * 3; i += 256) {
            int r = i / 3, k = i % 3;
            Lc[r][TW + 8 + k] = Lc[r][TW + 6 - k]; // col S+k <- col S-2-k
        }
    }
    if (tx0 == 0 || tx0 + TW == S) __syncthreads();

    // ---- phase 2: horizontal 5-tap at down col xd0-1+xh
    for (int i = tid; i < RC * CH; i += 256) {
        int r = i / CH, xh = i % CH;
        int c = 2 * xh + 4;
        Lh[r][xh] = Lc[r][c] + 4.f * Lc[r][c + 1] + 6.f * Lc[r][c + 2]
                  + 4.f * Lc[r][c + 3] + Lc[r][c + 4];
    }
    __syncthreads();

    // ---- phase 3: vertical 5-tap -> down tile (halo included)
    for (int i = tid; i < RD * CH; i += 256) {
        int yh = i / CH, xh = i % CH;
        int r = 2 * yh;
        Ld[yh][xh] = (Lh[r][xh] + 4.f * Lh[r + 1][xh] + 6.f * Lh[r + 2][xh]
                    + 4.f * Lh[r + 3][xh] + Lh[r + 4][xh]) * (1.f / 256.f);
    }
    __syncthreads();

    // ---- phase 3b: write interior down to global (next level's input)
    {
        size_t dbase = (size_t)n * D * D;
        constexpr int CW4 = TW / 8;
        for (int i = tid; i < (TH / 2) * CW4; i += 256) {
            int rr = i / CW4, k = i % CW4;
            float4 o4;
            o4.x = Ld[1 + rr][1 + 4 * k];
            o4.y = Ld[1 + rr][2 + 4 * k];
            o4.z = Ld[1 + rr][3 + 4 * k];
            o4.w = Ld[1 + rr][4 + 4 * k];
            *(float4*)(dwn + dbase + (size_t)(yd0 + rr) * D + xd0 + 4 * k) = o4;
        }
    }

    // ---- phase 4: up + |cur - up| on 2x2 quads (shared 3x3 down taps)
    float sum = 0.f;
    for (int i = tid; i < (TH / 2) * (TW / 2); i += 256) {
        int yh2 = i / (TW / 2), q = i % (TW / 2);
        float A00 = Ld[yh2][q],     A01 = Ld[yh2][q + 1],     A02 = Ld[yh2][q + 2];
        float A10 = Ld[yh2 + 1][q], A11 = Ld[yh2 + 1][q + 1], A12 = Ld[yh2 + 1][q + 2];
        float A20 = Ld[yh2 + 2][q], A21 = Ld[yh2 + 2][q + 1], A22 = Ld[yh2 + 2][q + 2];
        float ex0 = (A00 + 6.f * A01 + A02) * 0.125f;
        float ex1 = (A10 + 6.f * A11 + A12) * 0.125f;
        float ex2 = (A20 + 6.f * A21 + A22) * 0.125f;
        float ox0 = (A01 + A02) * 0.5f;
        float ox1 = (A11 + A12) * 0.5f;
        float ox2 = (A21 + A22) * 0.5f;
        float uee = (ex0 + 6.f * ex1 + ex2) * 0.125f;
        float ueo = (ox0 + 6.f * ox1 + ox2) * 0.125f;
        float uoe = (ex1 + ex2) * 0.5f;
        float uoo = (ox1 + ox2) * 0.5f;
        int ry = 2 * yh2 + 4, cx = 2 * q + 8;
        sum += fabsf(Lc[ry][cx] - uee) + fabsf(Lc[ry][cx + 1] - ueo)
             + fabsf(Lc[ry + 1][cx] - uoe) + fabsf(Lc[ry + 1][cx + 1] - uoo);
    }

    #pragma unroll
    for (int o = 32; o > 0; o >>= 1) sum += __shfl_down(sum, o, 64);
    __shared__ float s[4];
    int lane = tid & 63, w = tid >> 6;
    if (lane == 0) s[w] = sum;
    __syncthreads();
    if (tid == 0) atomicAdd(&acc[bid & 63], (s[0] + s[1] + s[2] + s[3]) * scale);
}

// ---- in-LDS level: cur (SxS resident) -> dn (DxD); partial |cur-up| sum ----
__device__ float level_in_lds(const float* cur, float* h, float* dn,
                              int S, int tid, int nt) {
    const int D = S >> 1;
    for (int i = tid; i < S * D; i += nt) {
        int r = i / D, xh = i % D;
        int c0 = reflect_i(2 * xh - 2, S), c1 = reflect_i(2 * xh - 1, S);
        int c3 = 2 * xh + 1, c4 = reflect_i(2 * xh + 2, S);
        const float* row = cur + r * S;
        h[i] = row[c0] + 4.f * row[c1] + 6.f * row[2 * xh] + 4.f * row[c3] + row[c4];
    }
    wg_barrier();
    for (int i = tid; i < D * D; i += nt) {
        int yh = i / D, xh = i % D;
        int r0 = reflect_i(2 * yh - 2, S), r1 = reflect_i(2 * yh - 1, S);
        int r3 = 2 * yh + 1, r4 = reflect_i(2 * yh + 2, S);
        dn[i] = (h[r0 * D + xh] + 4.f * h[r1 * D + xh] + 6.f * h[2 * yh * D + xh]
               + 4.f * h[r3 * D + xh] + h[r4 * D + xh]) * (1.f / 256.f);
    }
    wg_barrier();
    float sum = 0.f;
    for (int i = tid; i < D * D; i += nt) {
        int yh2 = i / D, q = i % D;
        int rm = (yh2 == 0) ? 1 : yh2 - 1;
        int rp = (yh2 == D - 1) ? D - 1 : yh2 + 1;
        int cm = (q == 0) ? 1 : q - 1;
        int cp = (q == D - 1) ? D - 1 : q + 1;
        float A00 = dn[rm * D + cm], A01 = dn[rm * D + q], A02 = dn[rm * D + cp];
        float A10 = dn[yh2 * D + cm], A11 = dn[yh2 * D + q], A12 = dn[yh2 * D + cp];
        float A20 = dn[rp * D + cm], A21 = dn[rp * D + q], A22 = dn[rp * D + cp];
        float ex0 = (A00 + 6.f * A01 + A02) * 0.125f;
        float ex1 = (A10 + 6.f * A11 + A12) * 0.125f;
        float ex2 = (A20 + 6.f * A21 + A22) * 0.125f;
        float ox0 = (A01 + A02) * 0.5f;
        float ox1 = (A11 + A12) * 0.5f;
        float ox2 = (A21 + A22) * 0.5f;
        float uee = (ex0 + 6.f * ex1 + ex2) * 0.125f;
        float ueo = (ox0 + 6.f * ox1 + ox2) * 0.125f;
        float uoe = (ex1 + ex2) * 0.5f;
        float uoo = (ox1 + ox2) * 0.5f;
        const float* c0 = cur + (2 * yh2) * S + 2 * q;
        sum += fabsf(c0[0] - uee) + fabsf(c0[1] - ueo)
             + fabsf(c0[S] - uoe) + fabsf(c0[S + 1] - uoo);
    }
    wg_barrier();
    return sum;
}

// levels 2+3+4 per image: dn1 (128x128) -> all in LDS (R13/R15-proven).
__global__ __launch_bounds__(512, 1)
void tail_kernel(const float* __restrict__ d1, float* __restrict__ acc,
                 float s2, float s3, float s4) {
    __shared__ float cur[128 * 128];   // 64 KB; later reused for dn3, dn4
    __shared__ float hbuf[128 * 64];   // 32 KB; reused per level
    __shared__ float dn2[64 * 64];     // 16 KB
    int n = blockIdx.x, tid = threadIdx.x;
    const int nt = 512;
    const float4* src = (const float4*)(d1 + (size_t)n * 128 * 128);
    for (int i = tid; i < 128 * 32; i += nt) ((float4*)cur)[i] = src[i];
    wg_barrier();
    float sum = level_in_lds(cur, hbuf, dn2, 128, tid, nt) * s2;
    float* dn3 = cur;                  // 32*32, cur data now dead
    sum += level_in_lds(dn2, hbuf, dn3, 64, tid, nt) * s3;
    float* dn4 = cur + 32 * 32;        // 16*16
    sum += level_in_lds(dn3, hbuf, dn4, 32, tid, nt) * s4;
    #pragma unroll
    for (int o = 32; o > 0; o >>= 1) sum += __shfl_down(sum, o, 64);
    __shared__ float s[8];
    int lane = tid & 63, w = tid >> 6;
    if (lane == 0) s[w] = sum;
    wg_barrier();
    if (tid == 0) {
        float v = 0.f;
        #pragma unroll
        for (int i = 0; i < 8; i++) v += s[i];
        atomicAdd(&acc[n & 63], v);
    }
}

__global__ void finish_kernel(const float* __restrict__ acc, float* __restrict__ out) {
    float v = acc[threadIdx.x];
    #pragma unroll
    for (int o = 32; o > 0; o >>= 1) v += __shfl_down(v, o, 64);
    if (threadIdx.x == 0) out[0] = v;
}

extern "C" void kernel_launch(void* const* d_in, const int* in_sizes, int n_in,
                              void* d_out, int out_size, void* d_ws, size_t ws_size,
                              hipStream_t stream) {
    const float* p = (const float*)d_in[0];
    const float* t = (const float*)d_in[1];
    float* out = (float*)d_out;
    float* acc = (float*)d_ws;                    // 64 accumulator slots
    float* dn0 = acc + 64;                        // 48 * 256 * 256
    float* dn1 = dn0 + (size_t)48 * 256 * 256;    // 48 * 128 * 128

    hipMemsetAsync(acc, 0, 64 * sizeof(float), stream);

    const int N = 48;  // 16 batch * 3 channels (depthwise)

    // L0: S=512, 64x16 tiles -> 48*8*32 = 12288 blocks, 4 resident/CU
    fused_kernel<64, 16, 1><<<12288, 256, 0, stream>>>(
        p, t, dn0, acc, 512, 1.f / (float)(N * 512 * 512));
    // L1: S=256 -> 48*4*16 = 3072 blocks
    fused_kernel<64, 16, 0><<<3072, 256, 0, stream>>>(
        dn0, nullptr, dn1, acc, 256, 2.f / (float)(N * 256 * 256));
    // L2+L3+L4: one block per image, fully LDS-resident
    tail_kernel<<<N, 512, 0, stream>>>(dn1, acc,
                                       4.f / (float)(N * 128 * 128),
                                       8.f / (float)(N * 64 * 64),
                                       16.f / (float)(N * 32 * 32));
    finish_kernel<<<1, 64, 0, stream>>>(acc, out);
}

// Round 17
// 56.445 us; speedup vs baseline: 2.1871x; 2.1871x over previous
//
#include <hip/hip_runtime.h>

// Laplacian pyramid loss via linearity: pyr(p) - pyr(t) = pyr(p - t).
// R17 = R13 verbatim (best: 57.2us). FINAL STATE after the R16 matrix
// experiment failed (compiler register-minimizes to VGPR=16 regardless of
// launch_bounds; loads serialize). Ceiling ledger (R9-R16): six L0
// structures pin at 40+-3us = ~113MB demand / ~2.9-3.4 TB/s = per-direction
// read delivery rate (m13 6.29 TB/s copy is read+write summed; pure-write
// fill hits 6.9 TB/s). Killed: demand-BW (-15% bytes -> -3% time), occupancy
// (57%/61% occ slower than 7%), bytes-in-flight (287KB/CU -> 2.3 TB/s),
// bank conflicts (0 -> same), DMA-addr swizzle (linear==swizzled),
// chain-serialization (2 chains/wave null), VGPRxOccupancy (compiler
// collapses to min-reg codegen, 2 attempts).
// Floor arithmetic: L0 38 + L1 8 + tail 8 + gaps 3 ~= 57us.

__device__ __forceinline__ int reflect_i(int m, int S) {
    if (m < 0) m = -m;
    if (m >= S) m = 2 * S - 2 - m;
    return m;
}

__device__ __forceinline__ void wg_barrier() {
    asm volatile("s_waitcnt lgkmcnt(0)" ::: "memory");
    __builtin_amdgcn_s_barrier();
}

#define LGKM0 asm volatile("s_waitcnt lgkmcnt(0)" ::: "memory")

template <int N>
__device__ __forceinline__ void wait_vm() {
    if constexpr (N == 0)      asm volatile("s_waitcnt vmcnt(0)" ::: "memory");
    else if constexpr (N == 1) asm volatile("s_waitcnt vmcnt(1)" ::: "memory");
    else if constexpr (N == 2) asm volatile("s_waitcnt vmcnt(2)" ::: "memory");
    else if constexpr (N == 4) asm volatile("s_waitcnt vmcnt(4)" ::: "memory");
    else if constexpr (N == 8) asm volatile("s_waitcnt vmcnt(8)" ::: "memory");
}

__device__ __forceinline__ void gld16(const void* g, void* l) {
    __builtin_amdgcn_global_load_lds(
        (const __attribute__((address_space(1))) void*)g,
        (__attribute__((address_space(3))) void*)l, 16, 0, 0);
}

template <int S, int ISL0, int DH, int WPB>
__global__ __launch_bounds__(WPB * 64, 2)
void pyr_kernel(const float* __restrict__ a, const float* __restrict__ b,
                float* __restrict__ dwn, float* __restrict__ acc, float scale) {
    constexpr int D = S / 2;
    constexpr int CPL = S / 128;                  // down cols per lane: 4/2/1
    constexpr int ROWB = (CPL == 4) ? 2048 : 1024;
    constexpr int SLOT = ROWB * (ISL0 ? 2 : 1);
    constexpr int OPS = (CPL == 4) ? (ISL0 ? 4 : 2) : 1;  // gld16 per stage_row
    constexpr int NRS = D / DH;

    __shared__ float4 ringmem[WPB * 4 * SLOT / 16]; // WPB waves x 4 slots
    const int wv = threadIdx.x >> 6;
    const int lane = threadIdx.x & 63;
    char* ring = (char*)ringmem + wv * (4 * SLOT);

    const int wid = blockIdx.x * WPB + wv;
    const int rs = wid % NRS;
    const int n = wid / NRS;
    const int R0 = rs * DH;
    const size_t gbase = (size_t)n * S * S;

    auto stage_row = [&](int s) {
        int gr = reflect_i(2 * R0 - 4 + s, S);
        const char* ga = (const char*)(a + gbase + (size_t)gr * S);
        char* la = ring + (s & 3) * SLOT;
        if constexpr (CPL == 4) {
            gld16(ga + 16 * lane, la);
            gld16(ga + 16 * lane + 1024, la + 1024);
        } else if constexpr (CPL == 2) {
            gld16(ga + 16 * lane, la);
        } else {
            gld16(ga + 16 * (lane & 31), la);    // 512B row; lanes>=32 dup pad
        }
        if constexpr (ISL0) {
            const char* gb = (const char*)(b + gbase + (size_t)gr * S);
            gld16(gb + 16 * lane, la + ROWB);
            gld16(gb + 16 * lane + 1024, la + ROWB + 1024);
        }
    };

    // own-chunk reads + shuffle halos; fills c[2*CPL] (lane's cur cols) and
    // h[CPL] (horizontal 5-tap at the lane's down cols).
    auto proc_row = [&](int s, float* c, float* h) {
        const char* pa = ring + (s & 3) * SLOT;
        if constexpr (CPL == 4) {
            float4 x0 = *(const float4*)(pa + 16 * lane);           // cols 4l..
            float4 x1 = *(const float4*)(pa + 1024 + 16 * lane);    // cols 256+4l..
            if constexpr (ISL0) {
                const char* pb = pa + ROWB;
                float4 y0 = *(const float4*)(pb + 16 * lane);
                float4 y1 = *(const float4*)(pb + 1024 + 16 * lane);
                x0.x -= y0.x; x0.y -= y0.y; x0.z -= y0.z; x0.w -= y0.w;
                x1.x -= y1.x; x1.y -= y1.y; x1.z -= y1.z; x1.w -= y1.w;
            }
            c[0]=x0.x; c[1]=x0.y; c[2]=x0.z; c[3]=x0.w;
            c[4]=x1.x; c[5]=x1.y; c[6]=x1.z; c[7]=x1.w;
            float lu2  = __shfl_up(x0.z, 1, 64);
            float lu3  = __shfl_up(x0.w, 1, 64);
            float rd0  = __shfl_down(x0.x, 1, 64);
            float bcA  = __shfl(x1.x, 0, 64);     // col 256
            float lu2b = __shfl_up(x1.z, 1, 64);
            float lu3b = __shfl_up(x1.w, 1, 64);
            float rd0b = __shfl_down(x1.x, 1, 64);
            float bcZ  = __shfl(x0.z, 63, 64);    // col 254
            float bcW  = __shfl(x0.w, 63, 64);    // col 255
            float w0 = (lane == 0) ? x0.z : lu2;  // col 4l-2 (edge: col 2)
            float w1 = (lane == 0) ? x0.y : lu3;  // col 4l-1 (edge: col 1)
            float w6 = (lane == 63) ? bcA : rd0;  // col 4l+4 (boundary: 256)
            float v0 = (lane == 0) ? bcZ : lu2b;  // col 256+4l-2
            float v1 = (lane == 0) ? bcW : lu3b;  // col 256+4l-1
            float v6 = (lane == 63) ? x1.z : rd0b; // col 510 reflect
            h[0] = w0 + 4.f*w1 + 6.f*x0.x + 4.f*x0.y + x0.z;
            h[1] = x0.x + 4.f*x0.y + 6.f*x0.z + 4.f*x0.w + w6;
            h[2] = v0 + 4.f*v1 + 6.f*x1.x + 4.f*x1.y + x1.z;
            h[3] = x1.x + 4.f*x1.y + 6.f*x1.z + 4.f*x1.w + v6;
        } else if constexpr (CPL == 2) {
            float4 x0 = *(const float4*)(pa + 16 * lane);
            c[0]=x0.x; c[1]=x0.y; c[2]=x0.z; c[3]=x0.w;
            float lu2 = __shfl_up(x0.z, 1, 64);
            float lu3 = __shfl_up(x0.w, 1, 64);
            float rd0 = __shfl_down(x0.x, 1, 64);
            float w0 = (lane == 0) ? x0.z : lu2;
            float w1 = (lane == 0) ? x0.y : lu3;
            float w6 = (lane == 63) ? x0.z : rd0;  // col S -> S-2 reflect
            h[0] = w0 + 4.f*w1 + 6.f*x0.x + 4.f*x0.y + x0.z;
            h[1] = x0.x + 4.f*x0.y + 6.f*x0.z + 4.f*x0.w + w6;
        } else {
            float2 x0 = *(const float2*)(pa + 8 * lane);  // cols 2l, 2l+1
            c[0]=x0.x; c[1]=x0.y;
            float lu0 = __shfl_up(x0.x, 1, 64);
            float lu1 = __shfl_up(x0.y, 1, 64);
            float rd0 = __shfl_down(x0.x, 1, 64);
            float w0 = (lane == 0) ? rd0 : lu0;    // col 2l-2 (edge: col 2)
            float w1 = (lane == 0) ? x0.y : lu1;   // col 2l-1 (edge: col 1)
            float w4 = (lane == 63) ? x0.x : rd0;  // col 2l+2 (edge: S-2)
            h[0] = w0 + 4.f*w1 + 6.f*x0.x + 4.f*x0.y + w4;
        }
    };

    float hA[CPL], hB[CPL], hC[CPL], hD[CPL], hE[CPL];
    float cEv1[2*CPL], cEv2[2*CPL], cOd1[2*CPL], dump[2*CPL];
    float ex0[CPL] = {}, ex1[CPL] = {}, ox0[CPL] = {}, ox1[CPL] = {};
    float sum = 0.f;
    float* dbase = dwn + (size_t)n * D * D;

    // prologue: fill 4 slots, h for rows 0-2, refill freed slots with 4-6
    stage_row(0); stage_row(1); stage_row(2); stage_row(3);
    wait_vm<OPS>();                       // rows 0-2 landed (row 3 may fly)
    proc_row(0, dump, hA);
    proc_row(1, dump, hB);
    proc_row(2, dump, hC);
    LGKM0;
    stage_row(4); stage_row(5); stage_row(6);

    #pragma unroll
    for (int j = 0; j <= DH + 1; ++j) {
        const int m = R0 - 1 + j;
        if (j <= DH) wait_vm<2 * OPS>(); else wait_vm<0>();

        float c3[2*CPL], c4[2*CPL];
        proc_row(2 * j + 3, c3, hD);
        proc_row(2 * j + 4, c4, hE);

        float d[CPL], dl[CPL], dr[CPL], ex2[CPL], ox2[CPL];
        #pragma unroll
        for (int q = 0; q < CPL; q++)
            d[q] = (hA[q] + 4.f*hB[q] + 6.f*hC[q] + 4.f*hD[q] + hE[q]) * (1.f / 256.f);

        if constexpr (CPL == 4) {
            float su1 = __shfl_up(d[1], 1, 64);    // down col 2l-1
            float su3 = __shfl_up(d[3], 1, 64);    // down col 127+2l
            float sd0 = __shfl_down(d[0], 1, 64);  // down col 2l+2
            float sd2 = __shfl_down(d[2], 1, 64);  // down col 130+2l
            float bc1 = __shfl(d[1], 63, 64);      // down col 127
            float bc2 = __shfl(d[2], 0, 64);       // down col 128
            dl[0] = (lane == 0) ? d[1] : su1;      // col -1 -> 1
            dl[1] = d[0];
            dl[2] = (lane == 0) ? bc1 : su3;
            dl[3] = d[2];
            dr[0] = d[1];
            dr[1] = (lane == 63) ? bc2 : sd0;
            dr[2] = d[3];
            dr[3] = (lane == 63) ? d[3] : sd2;     // col D -> D-1
        } else if constexpr (CPL == 2) {
            float su1 = __shfl_up(d[1], 1, 64);
            float sd0 = __shfl_down(d[0], 1, 64);
            dl[0] = (lane == 0) ? d[1] : su1;
            dl[1] = d[0];
            dr[0] = d[1];
            dr[1] = (lane == 63) ? d[1] : sd0;
        } else {
            float su = __shfl_up(d[0], 1, 64);
            float sd = __shfl_down(d[0], 1, 64);
            dl[0] = (lane == 0) ? sd : su;
            dr[0] = (lane == 63) ? d[0] : sd;
        }
        #pragma unroll
        for (int q = 0; q < CPL; q++) {
            ex2[q] = 0.125f * (dl[q] + 6.f * d[q] + dr[q]);
            ox2[q] = 0.5f * (d[q] + dr[q]);
        }

        if (j >= 1 && j <= DH) {
            if constexpr (CPL == 4) {
                *(float2*)(dbase + (size_t)m * D + 2 * lane) = make_float2(d[0], d[1]);
                *(float2*)(dbase + (size_t)m * D + D / 2 + 2 * lane) = make_float2(d[2], d[3]);
            } else if constexpr (CPL == 2) {
                *(float2*)(dbase + (size_t)m * D + 2 * lane) = make_float2(d[0], d[1]);
            } else {
                dbase[(size_t)m * D + lane] = d[0];
            }
        }

        if (j >= 2) {
            const int me = m - 1;
            #pragma unroll
            for (int q = 0; q < CPL; q++) {
                float eA = (me == 0) ? ex2[q] : ex0[q];       // down row -1 -> 1
                float oA = (me == 0) ? ox2[q] : ox0[q];
                float eC = (me == D - 1) ? ex1[q] : ex2[q];   // down row D -> D-1
                float oC = (me == D - 1) ? ox1[q] : ox2[q];
                float uee = 0.125f * (eA + 6.f * ex1[q] + eC);
                float ueo = 0.125f * (oA + 6.f * ox1[q] + oC);
                float uoe = 0.5f * (ex1[q] + eC);
                float uoo = 0.5f * (ox1[q] + oC);
                sum += fabsf(cEv2[2*q]   - uee) + fabsf(cEv2[2*q+1] - ueo)
                     + fabsf(cOd1[2*q]   - uoe) + fabsf(cOd1[2*q+1] - uoo);
            }
        }

        #pragma unroll
        for (int q = 0; q < CPL; q++) {
            ex0[q] = ex1[q]; ex1[q] = ex2[q];
            ox0[q] = ox1[q]; ox1[q] = ox2[q];
            hA[q] = hC[q]; hB[q] = hD[q]; hC[q] = hE[q];
        }
        #pragma unroll
        for (int q = 0; q < 2 * CPL; q++) {
            cEv2[q] = cEv1[q];          // cur row seq 2j (even lap row)
            cEv1[q] = c4[q];            // seq 2j+4 -> lap @ j+2
            cOd1[q] = c3[q];            // seq 2j+3 -> lap @ j+1
        }

        if (j <= DH - 1) {
            LGKM0;                      // ds_reads retired before slot reuse
            stage_row(2 * j + 7);
            stage_row(2 * j + 8);
        }
    }

    #pragma unroll
    for (int o = 32; o > 0; o >>= 1) sum += __shfl_down(sum, o, 64);
    if (lane == 0) atomicAdd(&acc[wid & 63], sum * scale);
}

// ---- in-LDS level: cur (SxS resident) -> dn (DxD); partial |cur-up| sum ----
__device__ float level_in_lds(const float* cur, float* h, float* dn,
                              int S, int tid, int nt) {
    const int D = S >> 1;
    for (int i = tid; i < S * D; i += nt) {
        int r = i / D, xh = i % D;
        int c0 = reflect_i(2 * xh - 2, S), c1 = reflect_i(2 * xh - 1, S);
        int c3 = 2 * xh + 1, c4 = reflect_i(2 * xh + 2, S);
        const float* row = cur + r * S;
        h[i] = row[c0] + 4.f * row[c1] + 6.f * row[2 * xh] + 4.f * row[c3] + row[c4];
    }
    wg_barrier();
    for (int i = tid; i < D * D; i += nt) {
        int yh = i / D, xh = i % D;
        int r0 = reflect_i(2 * yh - 2, S), r1 = reflect_i(2 * yh - 1, S);
        int r3 = 2 * yh + 1, r4 = reflect_i(2 * yh + 2, S);
        dn[i] = (h[r0 * D + xh] + 4.f * h[r1 * D + xh] + 6.f * h[2 * yh * D + xh]
               + 4.f * h[r3 * D + xh] + h[r4 * D + xh]) * (1.f / 256.f);
    }
    wg_barrier();
    float sum = 0.f;
    for (int i = tid; i < D * D; i += nt) {
        int yh2 = i / D, q = i % D;
        int rm = (yh2 == 0) ? 1 : yh2 - 1;
        int rp = (yh2 == D - 1) ? D - 1 : yh2 + 1;
        int cm = (q == 0) ? 1 : q - 1;
        int cp = (q == D - 1) ? D - 1 : q + 1;
        float A00 = dn[rm * D + cm], A01 = dn[rm * D + q], A02 = dn[rm * D + cp];
        float A10 = dn[yh2 * D + cm], A11 = dn[yh2 * D + q], A12 = dn[yh2 * D + cp];
        float A20 = dn[rp * D + cm], A21 = dn[rp * D + q], A22 = dn[rp * D + cp];
        float ex0 = (A00 + 6.f * A01 + A02) * 0.125f;
        float ex1 = (A10 + 6.f * A11 + A12) * 0.125f;
        float ex2 = (A20 + 6.f * A21 + A22) * 0.125f;
        float ox0 = (A01 + A02) * 0.5f;
        float ox1 = (A11 + A12) * 0.5f;
        float ox2 = (A21 + A22) * 0.5f;
        float uee = (ex0 + 6.f * ex1 + ex2) * 0.125f;
        float ueo = (ox0 + 6.f * ox1 + ox2) * 0.125f;
        float uoe = (ex1 + ex2) * 0.5f;
        float uoo = (ox1 + ox2) * 0.5f;
        const float* c0 = cur + (2 * yh2) * S + 2 * q;
        sum += fabsf(c0[0] - uee) + fabsf(c0[1] - ueo)
             + fabsf(c0[S] - uoe) + fabsf(c0[S + 1] - uoo);
    }
    wg_barrier();
    return sum;
}

// levels 2+3+4 per image: dn1 (128x128) -> all in LDS (R6/R13-proven).
__global__ __launch_bounds__(512, 1)
void tail_kernel(const float* __restrict__ d1, float* __restrict__ acc,
                 float s2, float s3, float s4) {
    __shared__ float cur[128 * 128];   // 64 KB; later reused for dn3, dn4
    __shared__ float hbuf[128 * 64];   // 32 KB; reused per level
    __shared__ float dn2[64 * 64];     // 16 KB
    int n = blockIdx.x, tid = threadIdx.x;
    const int nt = 512;
    const float4* src = (const float4*)(d1 + (size_t)n * 128 * 128);
    for (int i = tid; i < 128 * 32; i += nt) ((float4*)cur)[i] = src[i];
    wg_barrier();
    float sum = level_in_lds(cur, hbuf, dn2, 128, tid, nt) * s2;
    float* dn3 = cur;                  // 32*32, cur data now dead
    sum += level_in_lds(dn2, hbuf, dn3, 64, tid, nt) * s3;
    float* dn4 = cur + 32 * 32;        // 16*16
    sum += level_in_lds(dn3, hbuf, dn4, 32, tid, nt) * s4;
    #pragma unroll
    for (int o = 32; o > 0; o >>= 1) sum += __shfl_down(sum, o, 64);
    __shared__ float s[8];
    int lane = tid & 63, w = tid >> 6;
    if (lane == 0) s[w] = sum;
    wg_barrier();
    if (tid == 0) {
        float v = 0.f;
        #pragma unroll
        for (int i = 0; i < 8; i++) v += s[i];
        atomicAdd(&acc[n & 63], v);
    }
}

__global__ void finish_kernel(const float* __restrict__ acc, float* __restrict__ out) {
    float v = acc[threadIdx.x];
    #pragma unroll
    for (int o = 32; o > 0; o >>= 1) v += __shfl_down(v, o, 64);
    if (threadIdx.x == 0) out[0] = v;
}

extern "C" void kernel_launch(void* const* d_in, const int* in_sizes, int n_in,
                              void* d_out, int out_size, void* d_ws, size_t ws_size,
                              hipStream_t stream) {
    const float* p = (const float*)d_in[0];
    const float* t = (const float*)d_in[1];
    float* out = (float*)d_out;
    float* acc = (float*)d_ws;                    // 64 accumulator slots
    float* dn0 = acc + 64;                        // 48 * 256 * 256
    float* dn1 = dn0 + (size_t)48 * 256 * 256;    // 48 * 128 * 128

    hipMemsetAsync(acc, 0, 64 * sizeof(float), stream);

    const int N = 48;  // 16 batch * 3 channels (depthwise)

    // L0: D=256, DH=16 -> 16 bands/img, 768 waves, WPB=2 -> 384 blocks
    pyr_kernel<512, 1, 16, 2><<<384, 128, 0, stream>>>(
        p, t, dn0, acc, 1.f / (float)(N * 512 * 512));
    // L1: D=128, DH=8 -> 16 bands/img, 768 waves, WPB=4 -> 192 blocks
    pyr_kernel<256, 0, 8, 4><<<192, 256, 0, stream>>>(
        dn0, nullptr, dn1, acc, 2.f / (float)(N * 256 * 256));
    // L2+L3+L4: one block per image, fully LDS-resident
    tail_kernel<<<N, 512, 0, stream>>>(dn1, acc,
                                       4.f / (float)(N * 128 * 128),
                                       8.f / (float)(N * 64 * 64),
                                       16.f / (float)(N * 32 * 32));
    finish_kernel<<<1, 64, 0, stream>>>(acc, out);
}